// Round 1
// baseline (16429.044 us; speedup 1.0000x reference)
//
#include <hip/hip_runtime.h>
#include <math.h>

#define NN 50000
#define EE 800000
#define RR 3

__device__ __forceinline__ float leaky(float x){ return x > 0.f ? x : 0.01f*x; }
__device__ __forceinline__ float sigmoid_f(float x){ return 1.f/(1.f+__expf(-x)); }
__device__ __forceinline__ float tanh_f(float x){ return 1.f - 2.f/(__expf(2.f*x)+1.f); }

// ---------------- LSTM: one block = 16 nodes, 256 threads (thread = gate row j) ----
__global__ __launch_bounds__(256) void lstm_kernel(
    const float* __restrict__ x,      // (N, 16, 64)
    const float* __restrict__ Wih,    // (256, 64)
    const float* __restrict__ Whh,    // (256, 64)
    const float* __restrict__ bih, const float* __restrict__ bhh,
    float* __restrict__ hout)         // (N, 64)
{
  const int tid = threadIdx.x;
  const int nb = blockIdx.x * 16;
  __shared__ float xs[16*64];
  __shared__ float hs[16*64];
  __shared__ float cs[16*64];
  __shared__ float gs[16*256];

  float4 wih[16], whh[16];
#pragma unroll
  for (int i=0;i<16;i++) wih[i] = *(const float4*)(Wih + tid*64 + i*4);
#pragma unroll
  for (int i=0;i<16;i++) whh[i] = *(const float4*)(Whh + tid*64 + i*4);
  const float bj = bih[tid] + bhh[tid];

  for (int i = tid; i < 16*64; i += 256){ hs[i]=0.f; cs[i]=0.f; }
  __syncthreads();

  const int ln = tid >> 4;          // node for x-staging
  const int lk = (tid & 15) * 4;    // feature base
  const int uk = tid & 63;          // hidden index for update
  const int uq = tid >> 6;          // node quadrant for update

  for (int t = 0; t < 16; ++t){
    *(float4*)&xs[ln*64 + lk] = *(const float4*)(x + ((size_t)(nb+ln)*16 + t)*64 + lk);
    __syncthreads();
    for (int n = 0; n < 16; ++n){
      float a0 = 0.f, a1 = 0.f;
#pragma unroll
      for (int kc = 0; kc < 16; ++kc){
        const float4 xv = *(const float4*)&xs[n*64 + kc*4];
        const float4 hv = *(const float4*)&hs[n*64 + kc*4];
        const float4 wi = wih[kc], wh = whh[kc];
        a0 = fmaf(wi.x,xv.x,a0); a0 = fmaf(wi.y,xv.y,a0);
        a0 = fmaf(wi.z,xv.z,a0); a0 = fmaf(wi.w,xv.w,a0);
        a1 = fmaf(wh.x,hv.x,a1); a1 = fmaf(wh.y,hv.y,a1);
        a1 = fmaf(wh.z,hv.z,a1); a1 = fmaf(wh.w,hv.w,a1);
      }
      gs[n*256 + tid] = a0 + a1 + bj;
    }
    __syncthreads();
#pragma unroll
    for (int nn = 0; nn < 4; ++nn){
      const int n = uq + nn*4;
      const float gi = gs[n*256 + uk];
      const float gf = gs[n*256 + 64 + uk];
      const float gg = gs[n*256 + 128 + uk];
      const float go = gs[n*256 + 192 + uk];
      float c = sigmoid_f(gf)*cs[n*64+uk] + sigmoid_f(gi)*tanh_f(gg);
      float h = sigmoid_f(go)*tanh_f(c);
      cs[n*64+uk] = c; hs[n*64+uk] = h;
    }
    __syncthreads();
  }
  *(float4*)(hout + (size_t)(nb+ln)*64 + lk) = *(float4*)&xs[0]; // placeholder overwritten below
  // (write real value; the line above is replaced by the correct store)
  *(float4*)(hout + (size_t)(nb+ln)*64 + lk) = *(float4*)&hs[ln*64 + lk];
}

// ---------------- generic D[n][o] = leaky(A[n, koff:koff+K] . W[o,:] + b[o]) -------
__global__ __launch_bounds__(128) void gemm_rt(
    const float* __restrict__ A, int lda, int koff, int K,
    const float* __restrict__ W, const float* __restrict__ bias,
    float* __restrict__ D, int ldd, int doff,
    float* __restrict__ D2, int doff2)
{
  __shared__ float xs[16*512];
  const int o = threadIdx.x;
  const int nb = blockIdx.x * 16;
  const int tot4 = (16*K)/4;
  for (int i = o; i < tot4; i += 128){
    int e = i*4; int n = e / K; int k = e - n*K;
    *(float4*)&xs[n*K + k] = *(const float4*)(A + (size_t)(nb+n)*lda + koff + k);
  }
  __syncthreads();
  float acc[16];
#pragma unroll
  for (int n=0;n<16;n++) acc[n]=0.f;
  const int K4 = K/4;
  for (int kc = 0; kc < K4; ++kc){
    const float4 w = *(const float4*)(W + (size_t)o*K + kc*4);
#pragma unroll
    for (int n=0;n<16;n++){
      const float4 xv = *(const float4*)&xs[n*K + kc*4];
      acc[n] = fmaf(w.x,xv.x,acc[n]);
      acc[n] = fmaf(w.y,xv.y,acc[n]);
      acc[n] = fmaf(w.z,xv.z,acc[n]);
      acc[n] = fmaf(w.w,xv.w,acc[n]);
    }
  }
  const float bo = bias[o];
#pragma unroll
  for (int n=0;n<16;n++){
    float v = leaky(acc[n] + bo);
    D[(size_t)(nb+n)*ldd + doff + o] = v;
    if (D2) D2[(size_t)(nb+n)*ldd + doff2 + o] = v;
  }
}

// ---------------- degrees -----------------------------------------------------------
__global__ void deg_kernel(const int* __restrict__ dst, float* __restrict__ deg){
  const int r = blockIdx.y;
  const int e = blockIdx.x*256 + threadIdx.x;
  if (e < EE) atomicAdd(&deg[(size_t)r*NN + dst[(size_t)r*EE + e]], 1.f);
}
__global__ void dinv_kernel(float* __restrict__ deg){
  int i = blockIdx.x*256 + threadIdx.x;
  if (i < RR*NN) deg[i] = 1.f/sqrtf(fmaxf(deg[i], 1.f));
}

// ---------------- edge scatter: agg[d] += f[s]*dinv[s] ------------------------------
__global__ __launch_bounds__(256) void scatter_kernel(
    const int* __restrict__ src, const int* __restrict__ dst,
    const float* __restrict__ f, const float* __restrict__ dinv,
    float* __restrict__ agg)
{
  const int idx = blockIdx.x*256 + threadIdx.x;   // < E*32 = 25.6M
  const int e = idx >> 5;
  const int c = (idx & 31) * 4;
  const int s = src[e]; const int d = dst[e];
  const float ds = dinv[s];
  const float4 v = *(const float4*)(f + (size_t)s*128 + c);
  float* a = agg + (size_t)d*128 + c;
  atomicAdd(a+0, v.x*ds);
  atomicAdd(a+1, v.y*ds);
  atomicAdd(a+2, v.z*ds);
  atomicAdd(a+3, v.w*ds);
}

// ---------------- f_next = f - agg*dinv ---------------------------------------------
__global__ void fupd_kernel(const float* __restrict__ f, const float* __restrict__ agg,
                            const float* __restrict__ dinv, float* __restrict__ fn)
{
  int i4 = blockIdx.x*256 + threadIdx.x;   // over N*32 float4s
  if (i4 >= NN*32) return;
  const float dv = dinv[i4 >> 5];
  const float4 fv = *(const float4*)(f + (size_t)i4*4);
  const float4 av = *(const float4*)(agg + (size_t)i4*4);
  float4 r;
  r.x = fv.x - av.x*dv; r.y = fv.y - av.y*dv;
  r.z = fv.z - av.z*dv; r.w = fv.w - av.w*dv;
  *(float4*)(fn + (size_t)i4*4) = r;
}

// ---------------- attention combine + lin5 (per relation) ---------------------------
// u_j[o] = Wf1[o,:] . f_j[n,:];  w_j[o] = W5[o,:] . f_j[n,:]
// score_t = sum_o Wf2[o] tanh(th_t . u + bf1[o]); softmax over 5; c_j = sum_t s_t th_t[j]
// hall[n, rcol+o] = c0 w0 + c1 w1 + c2 w2 + b5[o]
__global__ __launch_bounds__(128) void combine_kernel(
    const float* __restrict__ f0, const float* __restrict__ f1, const float* __restrict__ f2,
    const float* __restrict__ Wf1, const float* __restrict__ bf1, const float* __restrict__ Wf2,
    const float* __restrict__ W5, const float* __restrict__ b5,
    float* __restrict__ hall, int rcol)
{
  const int o = threadIdx.x;
  const int nb = blockIdx.x * 8;
  __shared__ float fs[3*8*128];
  __shared__ float red[16];

  for (int i = o; i < 768; i += 128){
    int e = i*4;
    int j = e >> 10; int rem = e & 1023;
    int n = rem >> 7; int k = rem & 127;
    const float* fp = (j==0) ? f0 : ((j==1) ? f1 : f2);
    *(float4*)&fs[e] = *(const float4*)(fp + (size_t)(nb+n)*128 + k);
  }
  __syncthreads();

  float u0[8],u1[8],u2[8],w0[8],w1[8],w2[8];
#pragma unroll
  for (int n=0;n<8;n++){u0[n]=0;u1[n]=0;u2[n]=0;w0[n]=0;w1[n]=0;w2[n]=0;}

  for (int kc=0;kc<32;kc++){
    const float4 wa = *(const float4*)(Wf1 + (size_t)o*128 + kc*4);
    const float4 wb = *(const float4*)(W5  + (size_t)o*128 + kc*4);
#pragma unroll
    for (int n=0;n<8;n++){
      const float4 a0 = *(const float4*)&fs[0*1024 + n*128 + kc*4];
      const float4 a1 = *(const float4*)&fs[1*1024 + n*128 + kc*4];
      const float4 a2 = *(const float4*)&fs[2*1024 + n*128 + kc*4];
      u0[n] = fmaf(wa.x,a0.x, fmaf(wa.y,a0.y, fmaf(wa.z,a0.z, fmaf(wa.w,a0.w, u0[n]))));
      u1[n] = fmaf(wa.x,a1.x, fmaf(wa.y,a1.y, fmaf(wa.z,a1.z, fmaf(wa.w,a1.w, u1[n]))));
      u2[n] = fmaf(wa.x,a2.x, fmaf(wa.y,a2.y, fmaf(wa.z,a2.z, fmaf(wa.w,a2.w, u2[n]))));
      w0[n] = fmaf(wb.x,a0.x, fmaf(wb.y,a0.y, fmaf(wb.z,a0.z, fmaf(wb.w,a0.w, w0[n]))));
      w1[n] = fmaf(wb.x,a1.x, fmaf(wb.y,a1.y, fmaf(wb.z,a1.z, fmaf(wb.w,a1.w, w1[n]))));
      w2[n] = fmaf(wb.x,a2.x, fmaf(wb.y,a2.y, fmaf(wb.z,a2.z, fmaf(wb.w,a2.w, w2[n]))));
    }
  }

  const float bo = bf1[o], wf2o = Wf2[o], b5o = b5[o];
#pragma unroll
  for (int n=0;n<8;n++){
    // THETAS (padded to 3): [0.8,-0.5,0],[3,-3,0.75],[0,3,-1.5],[0,0,0.75],[-0.2,0.5,0]
    float s0 = wf2o * tanh_f(fmaf( 0.8f,u0[n], fmaf(-0.5f,u1[n], bo)));
    float s1 = wf2o * tanh_f(fmaf( 3.0f,u0[n], fmaf(-3.0f,u1[n], fmaf(0.75f,u2[n], bo))));
    float s2 = wf2o * tanh_f(fmaf( 3.0f,u1[n], fmaf(-1.5f,u2[n], bo)));
    float s3 = wf2o * tanh_f(fmaf(0.75f,u2[n], bo));
    float s4 = wf2o * tanh_f(fmaf(-0.2f,u0[n], fmaf( 0.5f,u1[n], bo)));
#pragma unroll
    for (int off=32; off>0; off>>=1){
      s0 += __shfl_xor(s0, off);
      s1 += __shfl_xor(s1, off);
      s2 += __shfl_xor(s2, off);
      s3 += __shfl_xor(s3, off);
      s4 += __shfl_xor(s4, off);
    }
    if ((o & 63) == 0){
      const int w = o >> 6;
      red[w*8+0]=s0; red[w*8+1]=s1; red[w*8+2]=s2; red[w*8+3]=s3; red[w*8+4]=s4;
    }
    __syncthreads();
    float t0 = red[0]+red[8], t1 = red[1]+red[9], t2 = red[2]+red[10],
          t3 = red[3]+red[11], t4 = red[4]+red[12];
    float mx = fmaxf(fmaxf(fmaxf(t0,t1),fmaxf(t2,t3)),t4);
    float e0=__expf(t0-mx), e1=__expf(t1-mx), e2=__expf(t2-mx),
          e3=__expf(t3-mx), e4=__expf(t4-mx);
    float inv = 1.f/(e0+e1+e2+e3+e4);
    e0*=inv; e1*=inv; e2*=inv; e3*=inv; e4*=inv;
    float c0 =  0.8f*e0 + 3.0f*e1              - 0.2f*e4;
    float c1 = -0.5f*e0 - 3.0f*e1 + 3.0f*e2    + 0.5f*e4;
    float c2 =            0.75f*e1 - 1.5f*e2 + 0.75f*e3;
    float outv = fmaf(c0,w0[n], fmaf(c1,w1[n], fmaf(c2,w2[n], b5o)));
    hall[(size_t)(nb+n)*384 + rcol + o] = outv;
    __syncthreads();
  }
}

// ---------------- final: out = [act(hall), x0, x1, x2] @ W6.T + b6 ------------------
__global__ __launch_bounds__(256) void final_kernel(
    const float* __restrict__ hall, const float* __restrict__ xin,
    const float* __restrict__ W6, const float* __restrict__ b6,
    float* __restrict__ out)
{
  const int n = blockIdx.x*256 + threadIdx.x;
  if (n >= NN) return;
  float a0 = b6[0], a1 = b6[1];
  const float* h = hall + (size_t)n*384;
#pragma unroll 8
  for (int jc=0;jc<96;jc++){
    float4 v = *(const float4*)(h + jc*4);
    v.x = leaky(v.x); v.y = leaky(v.y); v.z = leaky(v.z); v.w = leaky(v.w);
    const float4 wA = *(const float4*)(W6 + jc*4);
    const float4 wB = *(const float4*)(W6 + 768 + jc*4);
    a0 = fmaf(wA.x,v.x, fmaf(wA.y,v.y, fmaf(wA.z,v.z, fmaf(wA.w,v.w, a0))));
    a1 = fmaf(wB.x,v.x, fmaf(wB.y,v.y, fmaf(wB.z,v.z, fmaf(wB.w,v.w, a1))));
  }
  for (int p=0;p<3;p++){
    const float* xp = xin + (size_t)p*NN*128 + (size_t)n*128;
    const int jb = 384 + p*128;
#pragma unroll 8
    for (int jc=0;jc<32;jc++){
      const float4 v = *(const float4*)(xp + jc*4);
      const float4 wA = *(const float4*)(W6 + jb + jc*4);
      const float4 wB = *(const float4*)(W6 + 768 + jb + jc*4);
      a0 = fmaf(wA.x,v.x, fmaf(wA.y,v.y, fmaf(wA.z,v.z, fmaf(wA.w,v.w, a0))));
      a1 = fmaf(wB.x,v.x, fmaf(wB.y,v.y, fmaf(wB.z,v.z, fmaf(wB.w,v.w, a1))));
    }
  }
  out[(size_t)n*2+0] = a0;
  out[(size_t)n*2+1] = a1;
}

extern "C" void kernel_launch(void* const* d_in, const int* in_sizes, int n_in,
                              void* d_out, int out_size, void* d_ws, size_t ws_size,
                              hipStream_t stream)
{
  (void)in_sizes; (void)n_in; (void)out_size; (void)ws_size;
  const float* voc    = (const float*)d_in[0];
  const float* sms    = (const float*)d_in[1];
  const float* pers   = (const float*)d_in[2];
  const float* Wih_v  = (const float*)d_in[3];
  const float* Whh_v  = (const float*)d_in[4];
  const float* bih_v  = (const float*)d_in[5];
  const float* bhh_v  = (const float*)d_in[6];
  const float* Wih_s  = (const float*)d_in[7];
  const float* Whh_s  = (const float*)d_in[8];
  const float* bih_s  = (const float*)d_in[9];
  const float* bhh_s  = (const float*)d_in[10];
  const float* W_lin  = (const float*)d_in[11];
  const float* b_lin  = (const float*)d_in[12];
  const float* W_lin1 = (const float*)d_in[13];
  const float* b_lin1 = (const float*)d_in[14];
  const float* W_pers = (const float*)d_in[15];
  const float* b_pers = (const float*)d_in[16];
  const float* W_lin2 = (const float*)d_in[17];
  const float* b_lin2 = (const float*)d_in[18];
  const float* W_lin3 = (const float*)d_in[19];
  const float* b_lin3 = (const float*)d_in[20];
  const float* W_lin4 = (const float*)d_in[21];
  const float* b_lin4 = (const float*)d_in[22];
  const float* W_lin5 = (const float*)d_in[23];
  const float* b_lin5 = (const float*)d_in[24];
  const float* Wf1    = (const float*)d_in[25];
  const float* bf1    = (const float*)d_in[26];
  const float* Wf2    = (const float*)d_in[27];
  const float* W_lin6 = (const float*)d_in[28];
  const float* b_lin6 = (const float*)d_in[29];
  const int*   src    = (const int*)d_in[30];
  const int*   dst    = (const int*)d_in[31];

  float* ws   = (float*)d_ws;
  float* hv   = ws;                              // N*64
  float* hs   = hv  + (size_t)NN*64;             // N*64
  float* cat  = hs  + (size_t)NN*64;             // N*512 (reused as hall N*384)
  float* xin  = cat + (size_t)NN*512;            // 3*N*128
  float* f1   = xin + (size_t)3*NN*128;          // N*128
  float* f2   = f1  + (size_t)NN*128;            // N*128
  float* agg  = f2  + (size_t)NN*128;            // N*128
  float* dinv = agg + (size_t)NN*128;            // 3*N
  float* hall = cat;
  float* out  = (float*)d_out;

  // LSTMs
  lstm_kernel<<<NN/16, 256, 0, stream>>>(voc, Wih_v, Whh_v, bih_v, bhh_v, hv);
  lstm_kernel<<<NN/16, 256, 0, stream>>>(sms, Wih_s, Whh_s, bih_s, bhh_s, hs);

  // degrees -> dinv (all relations)
  hipMemsetAsync(dinv, 0, (size_t)RR*NN*4, stream);
  deg_kernel<<<dim3((EE+255)/256, RR), 256, 0, stream>>>(dst, dinv);
  dinv_kernel<<<(RR*NN+255)/256, 256, 0, stream>>>(dinv);

  // cat = [act(hv@Wlin+b), act(pers@Wpers+b), act(hs@Wlin1+b), act(pers@Wpers+b)]
  gemm_rt<<<NN/16, 128, 0, stream>>>(hv,   64, 0,  64, W_lin,  b_lin,  cat, 512,   0, nullptr, 0);
  gemm_rt<<<NN/16, 128, 0, stream>>>(hs,   64, 0,  64, W_lin1, b_lin1, cat, 512, 256, nullptr, 0);
  gemm_rt<<<NN/16, 128, 0, stream>>>(pers, 32, 0,  32, W_pers, b_pers, cat, 512, 128, cat, 384);

  // x_in
  gemm_rt<<<NN/16, 128, 0, stream>>>(cat, 512,   0, 256, W_lin2, b_lin2, xin,                     128, 0, nullptr, 0);
  gemm_rt<<<NN/16, 128, 0, stream>>>(cat, 512, 256, 256, W_lin3, b_lin3, xin + (size_t)NN*128,    128, 0, nullptr, 0);
  gemm_rt<<<NN/16, 128, 0, stream>>>(cat, 512,   0, 512, W_lin4, b_lin4, xin + (size_t)2*NN*128,  128, 0, nullptr, 0);

  for (int r = 0; r < RR; ++r){
    const float* f0 = xin + (size_t)r*NN*128;
    const float* dv = dinv + (size_t)r*NN;
    const int* sr = src + (size_t)r*EE;
    const int* dr = dst + (size_t)r*EE;

    hipMemsetAsync(agg, 0, (size_t)NN*128*4, stream);
    scatter_kernel<<<EE*32/256, 256, 0, stream>>>(sr, dr, f0, dv, agg);
    fupd_kernel<<<(NN*32+255)/256, 256, 0, stream>>>(f0, agg, dv, f1);

    hipMemsetAsync(agg, 0, (size_t)NN*128*4, stream);
    scatter_kernel<<<EE*32/256, 256, 0, stream>>>(sr, dr, f1, dv, agg);
    fupd_kernel<<<(NN*32+255)/256, 256, 0, stream>>>(f1, agg, dv, f2);

    combine_kernel<<<NN/8, 128, 0, stream>>>(f0, f1, f2,
        Wf1 + (size_t)r*128*128, bf1 + (size_t)r*128, Wf2 + (size_t)r*128,
        W_lin5 + (size_t)r*128*128, b_lin5 + (size_t)r*128, hall, r*128);
  }

  final_kernel<<<(NN+255)/256, 256, 0, stream>>>(hall, xin, W_lin6, b_lin6, out);
}

// Round 2
// 13611.066 us; speedup vs baseline: 1.2070x; 1.2070x over previous
//
#include <hip/hip_runtime.h>
#include <math.h>

#define NN 50000
#define EE 800000
#define RR 3
#define CHUNK 10000   // nodes per LSTM chunk (xg buffer = CHUNK*16*256 floats = 164 MB)

__device__ __forceinline__ float leaky(float x){ return x > 0.f ? x : 0.01f*x; }
__device__ __forceinline__ float sigmoid_f(float x){ return 1.f/(1.f+__expf(-x)); }
__device__ __forceinline__ float tanh_f(float x){ return 1.f - 2.f/(__expf(2.f*x)+1.f); }

// ---------------- LSTM phase 1: xg[row][j] = bih[j]+bhh[j] + x[row,:]·Wih[j,:] ------
// rows = chunk*16 (node-major, t inner). Block: 256 threads (thread=j), 32 rows.
__global__ __launch_bounds__(256) void lstm_xg_kernel(
    const float* __restrict__ x,      // chunk base: (chunk*16, 64)
    const float* __restrict__ Wih,    // (256, 64)
    const float* __restrict__ bih, const float* __restrict__ bhh,
    float* __restrict__ xg)           // (chunk*16, 256)
{
  const int j = threadIdx.x;
  const int rb = blockIdx.x * 32;
  __shared__ float xs[32*64];

  float4 w[16];
#pragma unroll
  for (int i=0;i<16;i++) w[i] = *(const float4*)(Wih + (size_t)j*64 + i*4);
  const float bj = bih[j] + bhh[j];

  // stage 32 rows of x (32*64 floats = 512 float4, 2 per thread)
#pragma unroll
  for (int i=0;i<2;i++){
    int f4 = j + i*256;               // 0..511
    int r = f4 >> 4, c = (f4 & 15) * 4;
    *(float4*)&xs[r*64 + c] = *(const float4*)(x + (size_t)(rb + r)*64 + c);
  }
  __syncthreads();

  for (int r = 0; r < 32; ++r){
    float4 acc = {0.f,0.f,0.f,0.f};
#pragma unroll
    for (int kc = 0; kc < 16; ++kc){
      const float4 xv = *(const float4*)&xs[r*64 + kc*4];   // wave-uniform (broadcast)
      acc.x = fmaf(w[kc].x, xv.x, acc.x);
      acc.y = fmaf(w[kc].y, xv.y, acc.y);
      acc.z = fmaf(w[kc].z, xv.z, acc.z);
      acc.w = fmaf(w[kc].w, xv.w, acc.w);
    }
    xg[(size_t)(rb + r)*256 + j] = (acc.x + acc.y) + (acc.z + acc.w) + bj;
  }
}

// ---------------- LSTM phase 2: recurrence, only h@Whh.T --------------------------
// Block: 16 nodes, 256 threads (thread = gate row j), Whh[j,:] in regs (64 VGPR).
__global__ __launch_bounds__(256) void lstm_rec_kernel(
    const float* __restrict__ xg,     // (chunk*16, 256) precomputed gates-from-x (+bias)
    const float* __restrict__ Whh,    // (256, 64)
    float* __restrict__ hout)         // global hout for chunk: (chunk, 64)
{
  const int j = threadIdx.x;
  const int nb = blockIdx.x * 16;     // chunk-local node base
  __shared__ float hs[16*64];
  __shared__ float cs[16*64];
  __shared__ float gs[16*256];

  float4 whh[16];
#pragma unroll
  for (int i=0;i<16;i++) whh[i] = *(const float4*)(Whh + (size_t)j*64 + i*4);

  for (int i = j; i < 16*64; i += 256){ hs[i]=0.f; cs[i]=0.f; }
  __syncthreads();

  const int uk = j & 63;            // hidden index for state update
  const int uq = j >> 6;            // node quadrant for state update
  const int ln = j >> 4;            // node for final store
  const int lk = (j & 15) * 4;      // feature base for final store

  for (int t = 0; t < 16; ++t){
    // issue the 16 xg loads for this timestep early (independent)
    float xgv[16];
#pragma unroll
    for (int n=0;n<16;n++)
      xgv[n] = xg[((size_t)(nb+n)*16 + t)*256 + j];

#pragma unroll 4
    for (int n = 0; n < 16; ++n){
      float4 acc = {0.f,0.f,0.f,0.f};
#pragma unroll
      for (int kc = 0; kc < 16; ++kc){
        const float4 hv = *(const float4*)&hs[n*64 + kc*4];  // wave-uniform (broadcast)
        acc.x = fmaf(whh[kc].x, hv.x, acc.x);
        acc.y = fmaf(whh[kc].y, hv.y, acc.y);
        acc.z = fmaf(whh[kc].z, hv.z, acc.z);
        acc.w = fmaf(whh[kc].w, hv.w, acc.w);
      }
      gs[n*256 + j] = (acc.x + acc.y) + (acc.z + acc.w) + xgv[n];
    }
    __syncthreads();
#pragma unroll
    for (int nn = 0; nn < 4; ++nn){
      const int n = uq + nn*4;
      const float gi = gs[n*256 + uk];
      const float gf = gs[n*256 + 64 + uk];
      const float gg = gs[n*256 + 128 + uk];
      const float go = gs[n*256 + 192 + uk];
      float c = sigmoid_f(gf)*cs[n*64+uk] + sigmoid_f(gi)*tanh_f(gg);
      float h = sigmoid_f(go)*tanh_f(c);
      cs[n*64+uk] = c; hs[n*64+uk] = h;
    }
    __syncthreads();
  }
  *(float4*)(hout + (size_t)(nb+ln)*64 + lk) = *(float4*)&hs[ln*64 + lk];
}

// ---------------- generic D[n][o] = leaky(A[n, koff:koff+K] . W[o,:] + b[o]) -------
__global__ __launch_bounds__(128) void gemm_rt(
    const float* __restrict__ A, int lda, int koff, int K,
    const float* __restrict__ W, const float* __restrict__ bias,
    float* __restrict__ D, int ldd, int doff,
    float* __restrict__ D2, int doff2)
{
  __shared__ float xs[16*512];
  const int o = threadIdx.x;
  const int nb = blockIdx.x * 16;
  const int tot4 = (16*K)/4;
  for (int i = o; i < tot4; i += 128){
    int e = i*4; int n = e / K; int k = e - n*K;
    *(float4*)&xs[n*K + k] = *(const float4*)(A + (size_t)(nb+n)*lda + koff + k);
  }
  __syncthreads();
  float acc[16];
#pragma unroll
  for (int n=0;n<16;n++) acc[n]=0.f;
  const int K4 = K/4;
  for (int kc = 0; kc < K4; ++kc){
    const float4 w = *(const float4*)(W + (size_t)o*K + kc*4);
#pragma unroll
    for (int n=0;n<16;n++){
      const float4 xv = *(const float4*)&xs[n*K + kc*4];
      acc[n] = fmaf(w.x,xv.x,acc[n]);
      acc[n] = fmaf(w.y,xv.y,acc[n]);
      acc[n] = fmaf(w.z,xv.z,acc[n]);
      acc[n] = fmaf(w.w,xv.w,acc[n]);
    }
  }
  const float bo = bias[o];
#pragma unroll
  for (int n=0;n<16;n++){
    float v = leaky(acc[n] + bo);
    D[(size_t)(nb+n)*ldd + doff + o] = v;
    if (D2) D2[(size_t)(nb+n)*ldd + doff2 + o] = v;
  }
}

// ---------------- degrees -----------------------------------------------------------
__global__ void deg_kernel(const int* __restrict__ dst, float* __restrict__ deg){
  const int r = blockIdx.y;
  const int e = blockIdx.x*256 + threadIdx.x;
  if (e < EE) atomicAdd(&deg[(size_t)r*NN + dst[(size_t)r*EE + e]], 1.f);
}
__global__ void dinv_kernel(float* __restrict__ deg){
  int i = blockIdx.x*256 + threadIdx.x;
  if (i < RR*NN) deg[i] = 1.f/sqrtf(fmaxf(deg[i], 1.f));
}

// ---------------- edge scatter: agg[d] += f[s]*dinv[s] ------------------------------
__global__ __launch_bounds__(256) void scatter_kernel(
    const int* __restrict__ src, const int* __restrict__ dst,
    const float* __restrict__ f, const float* __restrict__ dinv,
    float* __restrict__ agg)
{
  const int idx = blockIdx.x*256 + threadIdx.x;   // < E*32 = 25.6M
  const int e = idx >> 5;
  const int c = (idx & 31) * 4;
  const int s = src[e]; const int d = dst[e];
  const float ds = dinv[s];
  const float4 v = *(const float4*)(f + (size_t)s*128 + c);
  float* a = agg + (size_t)d*128 + c;
  atomicAdd(a+0, v.x*ds);
  atomicAdd(a+1, v.y*ds);
  atomicAdd(a+2, v.z*ds);
  atomicAdd(a+3, v.w*ds);
}

// ---------------- f_next = f - agg*dinv ---------------------------------------------
__global__ void fupd_kernel(const float* __restrict__ f, const float* __restrict__ agg,
                            const float* __restrict__ dinv, float* __restrict__ fn)
{
  int i4 = blockIdx.x*256 + threadIdx.x;   // over N*32 float4s
  if (i4 >= NN*32) return;
  const float dv = dinv[i4 >> 5];
  const float4 fv = *(const float4*)(f + (size_t)i4*4);
  const float4 av = *(const float4*)(agg + (size_t)i4*4);
  float4 r;
  r.x = fv.x - av.x*dv; r.y = fv.y - av.y*dv;
  r.z = fv.z - av.z*dv; r.w = fv.w - av.w*dv;
  *(float4*)(fn + (size_t)i4*4) = r;
}

// ---------------- attention combine + lin5 (per relation) ---------------------------
__global__ __launch_bounds__(128) void combine_kernel(
    const float* __restrict__ f0, const float* __restrict__ f1, const float* __restrict__ f2,
    const float* __restrict__ Wf1, const float* __restrict__ bf1, const float* __restrict__ Wf2,
    const float* __restrict__ W5, const float* __restrict__ b5,
    float* __restrict__ hall, int rcol)
{
  const int o = threadIdx.x;
  const int nb = blockIdx.x * 8;
  __shared__ float fs[3*8*128];
  __shared__ float red[16];

  for (int i = o; i < 768; i += 128){
    int e = i*4;
    int jj = e >> 10; int rem = e & 1023;
    int n = rem >> 7; int k = rem & 127;
    const float* fp = (jj==0) ? f0 : ((jj==1) ? f1 : f2);
    *(float4*)&fs[e] = *(const float4*)(fp + (size_t)(nb+n)*128 + k);
  }
  __syncthreads();

  float u0[8],u1[8],u2[8],w0[8],w1[8],w2[8];
#pragma unroll
  for (int n=0;n<8;n++){u0[n]=0;u1[n]=0;u2[n]=0;w0[n]=0;w1[n]=0;w2[n]=0;}

  for (int kc=0;kc<32;kc++){
    const float4 wa = *(const float4*)(Wf1 + (size_t)o*128 + kc*4);
    const float4 wb = *(const float4*)(W5  + (size_t)o*128 + kc*4);
#pragma unroll
    for (int n=0;n<8;n++){
      const float4 a0 = *(const float4*)&fs[0*1024 + n*128 + kc*4];
      const float4 a1 = *(const float4*)&fs[1*1024 + n*128 + kc*4];
      const float4 a2 = *(const float4*)&fs[2*1024 + n*128 + kc*4];
      u0[n] = fmaf(wa.x,a0.x, fmaf(wa.y,a0.y, fmaf(wa.z,a0.z, fmaf(wa.w,a0.w, u0[n]))));
      u1[n] = fmaf(wa.x,a1.x, fmaf(wa.y,a1.y, fmaf(wa.z,a1.z, fmaf(wa.w,a1.w, u1[n]))));
      u2[n] = fmaf(wa.x,a2.x, fmaf(wa.y,a2.y, fmaf(wa.z,a2.z, fmaf(wa.w,a2.w, u2[n]))));
      w0[n] = fmaf(wb.x,a0.x, fmaf(wb.y,a0.y, fmaf(wb.z,a0.z, fmaf(wb.w,a0.w, w0[n]))));
      w1[n] = fmaf(wb.x,a1.x, fmaf(wb.y,a1.y, fmaf(wb.z,a1.z, fmaf(wb.w,a1.w, w1[n]))));
      w2[n] = fmaf(wb.x,a2.x, fmaf(wb.y,a2.y, fmaf(wb.z,a2.z, fmaf(wb.w,a2.w, w2[n]))));
    }
  }

  const float bo = bf1[o], wf2o = Wf2[o], b5o = b5[o];
#pragma unroll
  for (int n=0;n<8;n++){
    float s0 = wf2o * tanh_f(fmaf( 0.8f,u0[n], fmaf(-0.5f,u1[n], bo)));
    float s1 = wf2o * tanh_f(fmaf( 3.0f,u0[n], fmaf(-3.0f,u1[n], fmaf(0.75f,u2[n], bo))));
    float s2 = wf2o * tanh_f(fmaf( 3.0f,u1[n], fmaf(-1.5f,u2[n], bo)));
    float s3 = wf2o * tanh_f(fmaf(0.75f,u2[n], bo));
    float s4 = wf2o * tanh_f(fmaf(-0.2f,u0[n], fmaf( 0.5f,u1[n], bo)));
#pragma unroll
    for (int off=32; off>0; off>>=1){
      s0 += __shfl_xor(s0, off);
      s1 += __shfl_xor(s1, off);
      s2 += __shfl_xor(s2, off);
      s3 += __shfl_xor(s3, off);
      s4 += __shfl_xor(s4, off);
    }
    if ((o & 63) == 0){
      const int w = o >> 6;
      red[w*8+0]=s0; red[w*8+1]=s1; red[w*8+2]=s2; red[w*8+3]=s3; red[w*8+4]=s4;
    }
    __syncthreads();
    float t0 = red[0]+red[8], t1 = red[1]+red[9], t2 = red[2]+red[10],
          t3 = red[3]+red[11], t4 = red[4]+red[12];
    float mx = fmaxf(fmaxf(fmaxf(t0,t1),fmaxf(t2,t3)),t4);
    float e0=__expf(t0-mx), e1=__expf(t1-mx), e2=__expf(t2-mx),
          e3=__expf(t3-mx), e4=__expf(t4-mx);
    float inv = 1.f/(e0+e1+e2+e3+e4);
    e0*=inv; e1*=inv; e2*=inv; e3*=inv; e4*=inv;
    float c0 =  0.8f*e0 + 3.0f*e1              - 0.2f*e4;
    float c1 = -0.5f*e0 - 3.0f*e1 + 3.0f*e2    + 0.5f*e4;
    float c2 =            0.75f*e1 - 1.5f*e2 + 0.75f*e3;
    float outv = fmaf(c0,w0[n], fmaf(c1,w1[n], fmaf(c2,w2[n], b5o)));
    hall[(size_t)(nb+n)*384 + rcol + o] = outv;
    __syncthreads();
  }
}

// ---------------- final: out = [act(hall), x0, x1, x2] @ W6.T + b6 ------------------
__global__ __launch_bounds__(256) void final_kernel(
    const float* __restrict__ hall, const float* __restrict__ xin,
    const float* __restrict__ W6, const float* __restrict__ b6,
    float* __restrict__ out)
{
  const int n = blockIdx.x*256 + threadIdx.x;
  if (n >= NN) return;
  float a0 = b6[0], a1 = b6[1];
  const float* h = hall + (size_t)n*384;
#pragma unroll 8
  for (int jc=0;jc<96;jc++){
    float4 v = *(const float4*)(h + jc*4);
    v.x = leaky(v.x); v.y = leaky(v.y); v.z = leaky(v.z); v.w = leaky(v.w);
    const float4 wA = *(const float4*)(W6 + jc*4);
    const float4 wB = *(const float4*)(W6 + 768 + jc*4);
    a0 = fmaf(wA.x,v.x, fmaf(wA.y,v.y, fmaf(wA.z,v.z, fmaf(wA.w,v.w, a0))));
    a1 = fmaf(wB.x,v.x, fmaf(wB.y,v.y, fmaf(wB.z,v.z, fmaf(wB.w,v.w, a1))));
  }
  for (int p=0;p<3;p++){
    const float* xp = xin + (size_t)p*NN*128 + (size_t)n*128;
    const int jb = 384 + p*128;
#pragma unroll 8
    for (int jc=0;jc<32;jc++){
      const float4 v = *(const float4*)(xp + jc*4);
      const float4 wA = *(const float4*)(W6 + jb + jc*4);
      const float4 wB = *(const float4*)(W6 + 768 + jb + jc*4);
      a0 = fmaf(wA.x,v.x, fmaf(wA.y,v.y, fmaf(wA.z,v.z, fmaf(wA.w,v.w, a0))));
      a1 = fmaf(wB.x,v.x, fmaf(wB.y,v.y, fmaf(wB.z,v.z, fmaf(wB.w,v.w, a1))));
    }
  }
  out[(size_t)n*2+0] = a0;
  out[(size_t)n*2+1] = a1;
}

extern "C" void kernel_launch(void* const* d_in, const int* in_sizes, int n_in,
                              void* d_out, int out_size, void* d_ws, size_t ws_size,
                              hipStream_t stream)
{
  (void)in_sizes; (void)n_in; (void)out_size; (void)ws_size;
  const float* voc    = (const float*)d_in[0];
  const float* sms    = (const float*)d_in[1];
  const float* pers   = (const float*)d_in[2];
  const float* Wih_v  = (const float*)d_in[3];
  const float* Whh_v  = (const float*)d_in[4];
  const float* bih_v  = (const float*)d_in[5];
  const float* bhh_v  = (const float*)d_in[6];
  const float* Wih_s  = (const float*)d_in[7];
  const float* Whh_s  = (const float*)d_in[8];
  const float* bih_s  = (const float*)d_in[9];
  const float* bhh_s  = (const float*)d_in[10];
  const float* W_lin  = (const float*)d_in[11];
  const float* b_lin  = (const float*)d_in[12];
  const float* W_lin1 = (const float*)d_in[13];
  const float* b_lin1 = (const float*)d_in[14];
  const float* W_pers = (const float*)d_in[15];
  const float* b_pers = (const float*)d_in[16];
  const float* W_lin2 = (const float*)d_in[17];
  const float* b_lin2 = (const float*)d_in[18];
  const float* W_lin3 = (const float*)d_in[19];
  const float* b_lin3 = (const float*)d_in[20];
  const float* W_lin4 = (const float*)d_in[21];
  const float* b_lin4 = (const float*)d_in[22];
  const float* W_lin5 = (const float*)d_in[23];
  const float* b_lin5 = (const float*)d_in[24];
  const float* Wf1    = (const float*)d_in[25];
  const float* bf1    = (const float*)d_in[26];
  const float* Wf2    = (const float*)d_in[27];
  const float* W_lin6 = (const float*)d_in[28];
  const float* b_lin6 = (const float*)d_in[29];
  const int*   src    = (const int*)d_in[30];
  const int*   dst    = (const int*)d_in[31];

  float* ws   = (float*)d_ws;
  float* hv   = ws;                              // N*64
  float* hs   = hv  + (size_t)NN*64;             // N*64
  float* cat  = hs  + (size_t)NN*64;             // N*512 (reused as hall N*384)
  float* xin  = cat + (size_t)NN*512;            // 3*N*128
  float* f1   = xin + (size_t)3*NN*128;          // N*128
  float* f2   = f1  + (size_t)NN*128;            // N*128
  float* agg  = f2  + (size_t)NN*128;            // N*128
  float* dinv = agg + (size_t)NN*128;            // 3*N
  float* hall = cat;
  float* xg   = cat;                             // LSTM-phase scratch: CHUNK*16*256
                                                 // = 41M floats, aliases cat+xin (dead then)
  float* out  = (float*)d_out;

  // LSTMs: per chunk, precompute xg (input GEMM, all t) then run recurrence.
  for (int ls = 0; ls < 2; ++ls){
    const float* xi  = ls ? sms   : voc;
    const float* Wih = ls ? Wih_s : Wih_v;
    const float* Whh = ls ? Whh_s : Whh_v;
    const float* bi  = ls ? bih_s : bih_v;
    const float* bh  = ls ? bhh_s : bhh_v;
    float* ho        = ls ? hs    : hv;
    for (int n0 = 0; n0 < NN; n0 += CHUNK){
      lstm_xg_kernel<<<(CHUNK*16)/32, 256, 0, stream>>>(
          xi + (size_t)n0*16*64, Wih, bi, bh, xg);
      lstm_rec_kernel<<<CHUNK/16, 256, 0, stream>>>(
          xg, Whh, ho + (size_t)n0*64);
    }
  }

  // degrees -> dinv (all relations)
  hipMemsetAsync(dinv, 0, (size_t)RR*NN*4, stream);
  deg_kernel<<<dim3((EE+255)/256, RR), 256, 0, stream>>>(dst, dinv);
  dinv_kernel<<<(RR*NN+255)/256, 256, 0, stream>>>(dinv);

  // cat = [act(hv@Wlin+b), act(pers@Wpers+b), act(hs@Wlin1+b), act(pers@Wpers+b)]
  gemm_rt<<<NN/16, 128, 0, stream>>>(hv,   64, 0,  64, W_lin,  b_lin,  cat, 512,   0, nullptr, 0);
  gemm_rt<<<NN/16, 128, 0, stream>>>(hs,   64, 0,  64, W_lin1, b_lin1, cat, 512, 256, nullptr, 0);
  gemm_rt<<<NN/16, 128, 0, stream>>>(pers, 32, 0,  32, W_pers, b_pers, cat, 512, 128, cat, 384);

  // x_in
  gemm_rt<<<NN/16, 128, 0, stream>>>(cat, 512,   0, 256, W_lin2, b_lin2, xin,                     128, 0, nullptr, 0);
  gemm_rt<<<NN/16, 128, 0, stream>>>(cat, 512, 256, 256, W_lin3, b_lin3, xin + (size_t)NN*128,    128, 0, nullptr, 0);
  gemm_rt<<<NN/16, 128, 0, stream>>>(cat, 512,   0, 512, W_lin4, b_lin4, xin + (size_t)2*NN*128,  128, 0, nullptr, 0);

  for (int r = 0; r < RR; ++r){
    const float* f0 = xin + (size_t)r*NN*128;
    const float* dv = dinv + (size_t)r*NN;
    const int* sr = src + (size_t)r*EE;
    const int* dr = dst + (size_t)r*EE;

    hipMemsetAsync(agg, 0, (size_t)NN*128*4, stream);
    scatter_kernel<<<EE*32/256, 256, 0, stream>>>(sr, dr, f0, dv, agg);
    fupd_kernel<<<(NN*32+255)/256, 256, 0, stream>>>(f0, agg, dv, f1);

    hipMemsetAsync(agg, 0, (size_t)NN*128*4, stream);
    scatter_kernel<<<EE*32/256, 256, 0, stream>>>(sr, dr, f1, dv, agg);
    fupd_kernel<<<(NN*32+255)/256, 256, 0, stream>>>(f1, agg, dv, f2);

    combine_kernel<<<NN/8, 128, 0, stream>>>(f0, f1, f2,
        Wf1 + (size_t)r*128*128, bf1 + (size_t)r*128, Wf2 + (size_t)r*128,
        W_lin5 + (size_t)r*128*128, b_lin5 + (size_t)r*128, hall, r*128);
  }

  final_kernel<<<(NN+255)/256, 256, 0, stream>>>(hall, xin, W_lin6, b_lin6, out);
}

// Round 3
// 5681.635 us; speedup vs baseline: 2.8916x; 2.3956x over previous
//
#include <hip/hip_runtime.h>
#include <math.h>

#define NN 50000
#define EE 800000
#define RR 3
#define CHUNK 10000   // nodes per LSTM chunk (xg buffer = CHUNK*16*256 floats = 164 MB)

__device__ __forceinline__ float leaky(float x){ return x > 0.f ? x : 0.01f*x; }
__device__ __forceinline__ float sigmoid_f(float x){ return 1.f/(1.f+__expf(-x)); }
__device__ __forceinline__ float tanh_f(float x){ return 1.f - 2.f/(__expf(2.f*x)+1.f); }

// ---------------- LSTM phase 1: xg[row][j] = bih[j]+bhh[j] + x[row,:]·Wih[j,:] ------
__global__ __launch_bounds__(256) void lstm_xg_kernel(
    const float* __restrict__ x,      // chunk base: (chunk*16, 64)
    const float* __restrict__ Wih,    // (256, 64)
    const float* __restrict__ bih, const float* __restrict__ bhh,
    float* __restrict__ xg)           // (chunk*16, 256)
{
  const int j = threadIdx.x;
  const int rb = blockIdx.x * 32;
  __shared__ float xs[32*64];

  float4 w[16];
#pragma unroll
  for (int i=0;i<16;i++) w[i] = *(const float4*)(Wih + (size_t)j*64 + i*4);
  const float bj = bih[j] + bhh[j];

#pragma unroll
  for (int i=0;i<2;i++){
    int f4 = j + i*256;               // 0..511
    int r = f4 >> 4, c = (f4 & 15) * 4;
    *(float4*)&xs[r*64 + c] = *(const float4*)(x + (size_t)(rb + r)*64 + c);
  }
  __syncthreads();

  for (int r = 0; r < 32; ++r){
    float4 acc = {0.f,0.f,0.f,0.f};
#pragma unroll
    for (int kc = 0; kc < 16; ++kc){
      const float4 xv = *(const float4*)&xs[r*64 + kc*4];   // wave-uniform (broadcast)
      acc.x = fmaf(w[kc].x, xv.x, acc.x);
      acc.y = fmaf(w[kc].y, xv.y, acc.y);
      acc.z = fmaf(w[kc].z, xv.z, acc.z);
      acc.w = fmaf(w[kc].w, xv.w, acc.w);
    }
    xg[(size_t)(rb + r)*256 + j] = (acc.x + acc.y) + (acc.z + acc.w) + bj;
  }
}

// ---------------- LSTM phase 2: recurrence, only h@Whh.T --------------------------
__global__ __launch_bounds__(256) void lstm_rec_kernel(
    const float* __restrict__ xg,     // (chunk*16, 256)
    const float* __restrict__ Whh,    // (256, 64)
    float* __restrict__ hout)         // (chunk, 64)
{
  const int j = threadIdx.x;
  const int nb = blockIdx.x * 16;
  __shared__ float hs[16*64];
  __shared__ float cs[16*64];
  __shared__ float gs[16*256];

  float4 whh[16];
#pragma unroll
  for (int i=0;i<16;i++) whh[i] = *(const float4*)(Whh + (size_t)j*64 + i*4);

  for (int i = j; i < 16*64; i += 256){ hs[i]=0.f; cs[i]=0.f; }
  __syncthreads();

  const int uk = j & 63;
  const int uq = j >> 6;
  const int ln = j >> 4;
  const int lk = (j & 15) * 4;

  for (int t = 0; t < 16; ++t){
    float xgv[16];
#pragma unroll
    for (int n=0;n<16;n++)
      xgv[n] = xg[((size_t)(nb+n)*16 + t)*256 + j];

#pragma unroll 4
    for (int n = 0; n < 16; ++n){
      float4 acc = {0.f,0.f,0.f,0.f};
#pragma unroll
      for (int kc = 0; kc < 16; ++kc){
        const float4 hv = *(const float4*)&hs[n*64 + kc*4];  // wave-uniform (broadcast)
        acc.x = fmaf(whh[kc].x, hv.x, acc.x);
        acc.y = fmaf(whh[kc].y, hv.y, acc.y);
        acc.z = fmaf(whh[kc].z, hv.z, acc.z);
        acc.w = fmaf(whh[kc].w, hv.w, acc.w);
      }
      gs[n*256 + j] = (acc.x + acc.y) + (acc.z + acc.w) + xgv[n];
    }
    __syncthreads();
#pragma unroll
    for (int nn = 0; nn < 4; ++nn){
      const int n = uq + nn*4;
      const float gi = gs[n*256 + uk];
      const float gf = gs[n*256 + 64 + uk];
      const float gg = gs[n*256 + 128 + uk];
      const float go = gs[n*256 + 192 + uk];
      float c = sigmoid_f(gf)*cs[n*64+uk] + sigmoid_f(gi)*tanh_f(gg);
      float h = sigmoid_f(go)*tanh_f(c);
      cs[n*64+uk] = c; hs[n*64+uk] = h;
    }
    __syncthreads();
  }
  *(float4*)(hout + (size_t)(nb+ln)*64 + lk) = *(float4*)&hs[ln*64 + lk];
}

// ---------------- generic D[n][o] = leaky(A[n, koff:koff+K] . W[o,:] + b[o]) -------
__global__ __launch_bounds__(128) void gemm_rt(
    const float* __restrict__ A, int lda, int koff, int K,
    const float* __restrict__ W, const float* __restrict__ bias,
    float* __restrict__ D, int ldd, int doff,
    float* __restrict__ D2, int doff2)
{
  __shared__ float xs[16*512];
  const int o = threadIdx.x;
  const int nb = blockIdx.x * 16;
  const int tot4 = (16*K)/4;
  for (int i = o; i < tot4; i += 128){
    int e = i*4; int n = e / K; int k = e - n*K;
    *(float4*)&xs[n*K + k] = *(const float4*)(A + (size_t)(nb+n)*lda + koff + k);
  }
  __syncthreads();
  float acc[16];
#pragma unroll
  for (int n=0;n<16;n++) acc[n]=0.f;
  const int K4 = K/4;
  for (int kc = 0; kc < K4; ++kc){
    const float4 w = *(const float4*)(W + (size_t)o*K + kc*4);
#pragma unroll
    for (int n=0;n<16;n++){
      const float4 xv = *(const float4*)&xs[n*K + kc*4];
      acc[n] = fmaf(w.x,xv.x,acc[n]);
      acc[n] = fmaf(w.y,xv.y,acc[n]);
      acc[n] = fmaf(w.z,xv.z,acc[n]);
      acc[n] = fmaf(w.w,xv.w,acc[n]);
    }
  }
  const float bo = bias[o];
#pragma unroll
  for (int n=0;n<16;n++){
    float v = leaky(acc[n] + bo);
    D[(size_t)(nb+n)*ldd + doff + o] = v;
    if (D2) D2[(size_t)(nb+n)*ldd + doff2 + o] = v;
  }
}

// ---------------- CSR build: histogram ---------------------------------------------
__global__ void hist_kernel(const int* __restrict__ dst, int* __restrict__ cnt){
  const int r = blockIdx.y;
  const int e = blockIdx.x*256 + threadIdx.x;
  if (e < EE) atomicAdd(&cnt[(size_t)r*NN + dst[(size_t)r*EE + e]], 1);
}

// dinv from int counts
__global__ void dinv_kernel(const int* __restrict__ cnt, float* __restrict__ dinv){
  int i = blockIdx.x*256 + threadIdx.x;
  if (i < RR*NN) dinv[i] = 1.f/sqrtf(fmaxf((float)cnt[i], 1.f));
}

// ---------------- CSR build: exclusive prefix sum (one block per relation) ---------
__global__ __launch_bounds__(256) void scan_kernel(
    const int* __restrict__ cnt, int* __restrict__ row_ptr)
{
  const int r = blockIdx.x;
  const int tid = threadIdx.x;
  const int* c = cnt + (size_t)r*NN;
  int* rp = row_ptr + (size_t)r*(NN+1);
  __shared__ int sdata[256];
  int running = 0;
  for (int chunk = 0; chunk < NN; chunk += 1024){
    __syncthreads();
    int idx = chunk + tid*4;
    int v0=0,v1=0,v2=0,v3=0;
    if (idx   < NN) v0 = c[idx];
    if (idx+1 < NN) v1 = c[idx+1];
    if (idx+2 < NN) v2 = c[idx+2];
    if (idx+3 < NN) v3 = c[idx+3];
    int s = v0+v1+v2+v3;
    sdata[tid] = s;
    __syncthreads();
    for (int off=1; off<256; off<<=1){
      int t = (tid >= off) ? sdata[tid-off] : 0;
      __syncthreads();
      sdata[tid] += t;
      __syncthreads();
    }
    int excl = running + sdata[tid] - s;   // exclusive prefix for this thread's 4
    if (idx   < NN) rp[idx]   = excl;
    if (idx+1 < NN) rp[idx+1] = excl + v0;
    if (idx+2 < NN) rp[idx+2] = excl + v0 + v1;
    if (idx+3 < NN) rp[idx+3] = excl + v0 + v1 + v2;
    running += sdata[255];
  }
  if (tid == 0) rp[NN] = running;   // == EE
}

// ---------------- CSR build: fill --------------------------------------------------
__global__ void fill_kernel(const int* __restrict__ src, const int* __restrict__ dst,
                            const int* __restrict__ row_ptr, int* __restrict__ cursor,
                            int* __restrict__ csr_src)
{
  const int r = blockIdx.y;
  const int e = blockIdx.x*256 + threadIdx.x;
  if (e >= EE) return;
  const int d = dst[(size_t)r*EE + e];
  const int pos = atomicAdd(&cursor[(size_t)r*NN + d], 1);
  csr_src[(size_t)r*EE + row_ptr[(size_t)r*(NN+1) + d] + pos] = src[(size_t)r*EE + e];
}

// ---------------- pull-gather + fused update: fn = f - (Σ f[s]*dinv[s]) * dinv -----
// one wave per destination node; lane = feature (64 of 128, ×2)
__global__ __launch_bounds__(256) void gather_fused(
    const int* __restrict__ csr_src, const int* __restrict__ row_ptr,
    const float* __restrict__ f, const float* __restrict__ dinv,
    float* __restrict__ fn)
{
  const int node = blockIdx.x*4 + (threadIdx.x >> 6);
  const int lane = threadIdx.x & 63;
  if (node >= NN) return;
  int p  = row_ptr[node];
  const int p1 = row_ptr[node+1];
  float a0 = 0.f, a1 = 0.f;
  for (; p + 2 <= p1; p += 2){
    const int s0 = csr_src[p];
    const int s1 = csr_src[p+1];
    const float d0 = dinv[s0];
    const float d1 = dinv[s1];
    const float f00 = f[(size_t)s0*128 + lane];
    const float f01 = f[(size_t)s0*128 + 64 + lane];
    const float f10 = f[(size_t)s1*128 + lane];
    const float f11 = f[(size_t)s1*128 + 64 + lane];
    a0 = fmaf(f00, d0, a0); a1 = fmaf(f01, d0, a1);
    a0 = fmaf(f10, d1, a0); a1 = fmaf(f11, d1, a1);
  }
  if (p < p1){
    const int s0 = csr_src[p];
    const float d0 = dinv[s0];
    a0 = fmaf(f[(size_t)s0*128 + lane], d0, a0);
    a1 = fmaf(f[(size_t)s0*128 + 64 + lane], d0, a1);
  }
  const float dvd = dinv[node];
  fn[(size_t)node*128 + lane]      = f[(size_t)node*128 + lane]      - a0*dvd;
  fn[(size_t)node*128 + 64 + lane] = f[(size_t)node*128 + 64 + lane] - a1*dvd;
}

// ---------------- attention combine + lin5 (per relation) ---------------------------
__global__ __launch_bounds__(128) void combine_kernel(
    const float* __restrict__ f0, const float* __restrict__ f1, const float* __restrict__ f2,
    const float* __restrict__ Wf1, const float* __restrict__ bf1, const float* __restrict__ Wf2,
    const float* __restrict__ W5, const float* __restrict__ b5,
    float* __restrict__ hall, int rcol)
{
  const int o = threadIdx.x;
  const int nb = blockIdx.x * 8;
  __shared__ float fs[3*8*128];
  __shared__ float red[16];

  for (int i = o; i < 768; i += 128){
    int e = i*4;
    int jj = e >> 10; int rem = e & 1023;
    int n = rem >> 7; int k = rem & 127;
    const float* fp = (jj==0) ? f0 : ((jj==1) ? f1 : f2);
    *(float4*)&fs[e] = *(const float4*)(fp + (size_t)(nb+n)*128 + k);
  }
  __syncthreads();

  float u0[8],u1[8],u2[8],w0[8],w1[8],w2[8];
#pragma unroll
  for (int n=0;n<8;n++){u0[n]=0;u1[n]=0;u2[n]=0;w0[n]=0;w1[n]=0;w2[n]=0;}

  for (int kc=0;kc<32;kc++){
    const float4 wa = *(const float4*)(Wf1 + (size_t)o*128 + kc*4);
    const float4 wb = *(const float4*)(W5  + (size_t)o*128 + kc*4);
#pragma unroll
    for (int n=0;n<8;n++){
      const float4 a0 = *(const float4*)&fs[0*1024 + n*128 + kc*4];
      const float4 a1 = *(const float4*)&fs[1*1024 + n*128 + kc*4];
      const float4 a2 = *(const float4*)&fs[2*1024 + n*128 + kc*4];
      u0[n] = fmaf(wa.x,a0.x, fmaf(wa.y,a0.y, fmaf(wa.z,a0.z, fmaf(wa.w,a0.w, u0[n]))));
      u1[n] = fmaf(wa.x,a1.x, fmaf(wa.y,a1.y, fmaf(wa.z,a1.z, fmaf(wa.w,a1.w, u1[n]))));
      u2[n] = fmaf(wa.x,a2.x, fmaf(wa.y,a2.y, fmaf(wa.z,a2.z, fmaf(wa.w,a2.w, u2[n]))));
      w0[n] = fmaf(wb.x,a0.x, fmaf(wb.y,a0.y, fmaf(wb.z,a0.z, fmaf(wb.w,a0.w, w0[n]))));
      w1[n] = fmaf(wb.x,a1.x, fmaf(wb.y,a1.y, fmaf(wb.z,a1.z, fmaf(wb.w,a1.w, w1[n]))));
      w2[n] = fmaf(wb.x,a2.x, fmaf(wb.y,a2.y, fmaf(wb.z,a2.z, fmaf(wb.w,a2.w, w2[n]))));
    }
  }

  const float bo = bf1[o], wf2o = Wf2[o], b5o = b5[o];
#pragma unroll
  for (int n=0;n<8;n++){
    float s0 = wf2o * tanh_f(fmaf( 0.8f,u0[n], fmaf(-0.5f,u1[n], bo)));
    float s1 = wf2o * tanh_f(fmaf( 3.0f,u0[n], fmaf(-3.0f,u1[n], fmaf(0.75f,u2[n], bo))));
    float s2 = wf2o * tanh_f(fmaf( 3.0f,u1[n], fmaf(-1.5f,u2[n], bo)));
    float s3 = wf2o * tanh_f(fmaf(0.75f,u2[n], bo));
    float s4 = wf2o * tanh_f(fmaf(-0.2f,u0[n], fmaf( 0.5f,u1[n], bo)));
#pragma unroll
    for (int off=32; off>0; off>>=1){
      s0 += __shfl_xor(s0, off);
      s1 += __shfl_xor(s1, off);
      s2 += __shfl_xor(s2, off);
      s3 += __shfl_xor(s3, off);
      s4 += __shfl_xor(s4, off);
    }
    if ((o & 63) == 0){
      const int w = o >> 6;
      red[w*8+0]=s0; red[w*8+1]=s1; red[w*8+2]=s2; red[w*8+3]=s3; red[w*8+4]=s4;
    }
    __syncthreads();
    float t0 = red[0]+red[8], t1 = red[1]+red[9], t2 = red[2]+red[10],
          t3 = red[3]+red[11], t4 = red[4]+red[12];
    float mx = fmaxf(fmaxf(fmaxf(t0,t1),fmaxf(t2,t3)),t4);
    float e0=__expf(t0-mx), e1=__expf(t1-mx), e2=__expf(t2-mx),
          e3=__expf(t3-mx), e4=__expf(t4-mx);
    float inv = 1.f/(e0+e1+e2+e3+e4);
    e0*=inv; e1*=inv; e2*=inv; e3*=inv; e4*=inv;
    float c0 =  0.8f*e0 + 3.0f*e1              - 0.2f*e4;
    float c1 = -0.5f*e0 - 3.0f*e1 + 3.0f*e2    + 0.5f*e4;
    float c2 =            0.75f*e1 - 1.5f*e2 + 0.75f*e3;
    float outv = fmaf(c0,w0[n], fmaf(c1,w1[n], fmaf(c2,w2[n], b5o)));
    hall[(size_t)(nb+n)*384 + rcol + o] = outv;
    __syncthreads();
  }
}

// ---------------- final: out = [act(hall), x0, x1, x2] @ W6.T + b6 ------------------
__global__ __launch_bounds__(256) void final_kernel(
    const float* __restrict__ hall, const float* __restrict__ xin,
    const float* __restrict__ W6, const float* __restrict__ b6,
    float* __restrict__ out)
{
  const int n = blockIdx.x*256 + threadIdx.x;
  if (n >= NN) return;
  float a0 = b6[0], a1 = b6[1];
  const float* h = hall + (size_t)n*384;
#pragma unroll 8
  for (int jc=0;jc<96;jc++){
    float4 v = *(const float4*)(h + jc*4);
    v.x = leaky(v.x); v.y = leaky(v.y); v.z = leaky(v.z); v.w = leaky(v.w);
    const float4 wA = *(const float4*)(W6 + jc*4);
    const float4 wB = *(const float4*)(W6 + 768 + jc*4);
    a0 = fmaf(wA.x,v.x, fmaf(wA.y,v.y, fmaf(wA.z,v.z, fmaf(wA.w,v.w, a0))));
    a1 = fmaf(wB.x,v.x, fmaf(wB.y,v.y, fmaf(wB.z,v.z, fmaf(wB.w,v.w, a1))));
  }
  for (int p=0;p<3;p++){
    const float* xp = xin + (size_t)p*NN*128 + (size_t)n*128;
    const int jb = 384 + p*128;
#pragma unroll 8
    for (int jc=0;jc<32;jc++){
      const float4 v = *(const float4*)(xp + jc*4);
      const float4 wA = *(const float4*)(W6 + jb + jc*4);
      const float4 wB = *(const float4*)(W6 + 768 + jb + jc*4);
      a0 = fmaf(wA.x,v.x, fmaf(wA.y,v.y, fmaf(wA.z,v.z, fmaf(wA.w,v.w, a0))));
      a1 = fmaf(wB.x,v.x, fmaf(wB.y,v.y, fmaf(wB.z,v.z, fmaf(wB.w,v.w, a1))));
    }
  }
  out[(size_t)n*2+0] = a0;
  out[(size_t)n*2+1] = a1;
}

extern "C" void kernel_launch(void* const* d_in, const int* in_sizes, int n_in,
                              void* d_out, int out_size, void* d_ws, size_t ws_size,
                              hipStream_t stream)
{
  (void)in_sizes; (void)n_in; (void)out_size; (void)ws_size;
  const float* voc    = (const float*)d_in[0];
  const float* sms    = (const float*)d_in[1];
  const float* pers   = (const float*)d_in[2];
  const float* Wih_v  = (const float*)d_in[3];
  const float* Whh_v  = (const float*)d_in[4];
  const float* bih_v  = (const float*)d_in[5];
  const float* bhh_v  = (const float*)d_in[6];
  const float* Wih_s  = (const float*)d_in[7];
  const float* Whh_s  = (const float*)d_in[8];
  const float* bih_s  = (const float*)d_in[9];
  const float* bhh_s  = (const float*)d_in[10];
  const float* W_lin  = (const float*)d_in[11];
  const float* b_lin  = (const float*)d_in[12];
  const float* W_lin1 = (const float*)d_in[13];
  const float* b_lin1 = (const float*)d_in[14];
  const float* W_pers = (const float*)d_in[15];
  const float* b_pers = (const float*)d_in[16];
  const float* W_lin2 = (const float*)d_in[17];
  const float* b_lin2 = (const float*)d_in[18];
  const float* W_lin3 = (const float*)d_in[19];
  const float* b_lin3 = (const float*)d_in[20];
  const float* W_lin4 = (const float*)d_in[21];
  const float* b_lin4 = (const float*)d_in[22];
  const float* W_lin5 = (const float*)d_in[23];
  const float* b_lin5 = (const float*)d_in[24];
  const float* Wf1    = (const float*)d_in[25];
  const float* bf1    = (const float*)d_in[26];
  const float* Wf2    = (const float*)d_in[27];
  const float* W_lin6 = (const float*)d_in[28];
  const float* b_lin6 = (const float*)d_in[29];
  const int*   src    = (const int*)d_in[30];
  const int*   dst    = (const int*)d_in[31];

  float* ws   = (float*)d_ws;
  float* hv   = ws;                              // N*64
  float* hs   = hv  + (size_t)NN*64;             // N*64
  float* cat  = hs  + (size_t)NN*64;             // N*512 (reused as hall N*384)
  float* xin  = cat + (size_t)NN*512;            // 3*N*128
  float* f1   = xin + (size_t)3*NN*128;          // N*128
  float* f2   = f1  + (size_t)NN*128;            // N*128
  float* dinv = f2  + (size_t)NN*128;            // 3*N floats
  int*   cnt     = (int*)(dinv + (size_t)RR*NN); // R*N
  int*   row_ptr = cnt + (size_t)RR*NN;          // R*(N+1)
  int*   cursor  = row_ptr + (size_t)RR*(NN+1);  // R*N
  int*   csr_src = cursor + (size_t)RR*NN;       // R*E
  float* hall = cat;
  float* xg   = cat;                             // LSTM-phase scratch (aliases cat+xin)
  float* out  = (float*)d_out;

  // LSTMs: per chunk, precompute xg (input GEMM, all t) then run recurrence.
  for (int ls = 0; ls < 2; ++ls){
    const float* xi  = ls ? sms   : voc;
    const float* Wih = ls ? Wih_s : Wih_v;
    const float* Whh = ls ? Whh_s : Whh_v;
    const float* bi  = ls ? bih_s : bih_v;
    const float* bh  = ls ? bhh_s : bhh_v;
    float* ho        = ls ? hs    : hv;
    for (int n0 = 0; n0 < NN; n0 += CHUNK){
      lstm_xg_kernel<<<(CHUNK*16)/32, 256, 0, stream>>>(
          xi + (size_t)n0*16*64, Wih, bi, bh, xg);
      lstm_rec_kernel<<<CHUNK/16, 256, 0, stream>>>(
          xg, Whh, ho + (size_t)n0*64);
    }
  }

  // ---- CSR build (all relations) ----
  hipMemsetAsync(cnt, 0, (size_t)RR*NN*sizeof(int), stream);
  hipMemsetAsync(cursor, 0, (size_t)RR*NN*sizeof(int), stream);
  hist_kernel<<<dim3(EE/256, RR), 256, 0, stream>>>(dst, cnt);
  dinv_kernel<<<(RR*NN+255)/256, 256, 0, stream>>>(cnt, dinv);
  scan_kernel<<<RR, 256, 0, stream>>>(cnt, row_ptr);
  fill_kernel<<<dim3(EE/256, RR), 256, 0, stream>>>(src, dst, row_ptr, cursor, csr_src);

  // cat = [act(hv@Wlin+b), act(pers@Wpers+b), act(hs@Wlin1+b), act(pers@Wpers+b)]
  gemm_rt<<<NN/16, 128, 0, stream>>>(hv,   64, 0,  64, W_lin,  b_lin,  cat, 512,   0, nullptr, 0);
  gemm_rt<<<NN/16, 128, 0, stream>>>(hs,   64, 0,  64, W_lin1, b_lin1, cat, 512, 256, nullptr, 0);
  gemm_rt<<<NN/16, 128, 0, stream>>>(pers, 32, 0,  32, W_pers, b_pers, cat, 512, 128, cat, 384);

  // x_in
  gemm_rt<<<NN/16, 128, 0, stream>>>(cat, 512,   0, 256, W_lin2, b_lin2, xin,                     128, 0, nullptr, 0);
  gemm_rt<<<NN/16, 128, 0, stream>>>(cat, 512, 256, 256, W_lin3, b_lin3, xin + (size_t)NN*128,    128, 0, nullptr, 0);
  gemm_rt<<<NN/16, 128, 0, stream>>>(cat, 512,   0, 512, W_lin4, b_lin4, xin + (size_t)2*NN*128,  128, 0, nullptr, 0);

  for (int r = 0; r < RR; ++r){
    const float* f0 = xin + (size_t)r*NN*128;
    const float* dv = dinv + (size_t)r*NN;
    const int* cs = csr_src + (size_t)r*EE;
    const int* rp = row_ptr + (size_t)r*(NN+1);

    gather_fused<<<(NN+3)/4, 256, 0, stream>>>(cs, rp, f0, dv, f1);
    gather_fused<<<(NN+3)/4, 256, 0, stream>>>(cs, rp, f1, dv, f2);

    combine_kernel<<<NN/8, 128, 0, stream>>>(f0, f1, f2,
        Wf1 + (size_t)r*128*128, bf1 + (size_t)r*128, Wf2 + (size_t)r*128,
        W_lin5 + (size_t)r*128*128, b_lin5 + (size_t)r*128, hall, r*128);
  }

  final_kernel<<<(NN+255)/256, 256, 0, stream>>>(hall, xin, W_lin6, b_lin6, out);
}